// Round 1
// baseline (358.718 us; speedup 1.0000x reference)
//
#include <hip/hip_runtime.h>

// Tensor-product nonlinearity, B=512, MUL=64, l in {0,1,2}.
// out0: (512, 3*4096, 1), out1: (512, 4*4096, 3), out2: (512, 4*4096, 5)
// flat-concatenated in d_out in that order.
//
// Round-3 design (J=4):
//  - each thread owns 4 consecutive c = i*64+j values (same i, j0..j0+3).
//  - a-side precontraction wa[n][M] = sum_m w[m][n][M] * a[m] computed once
//    per thread, reused for 4 j's  -> total FMA halved vs per-(i,j) form.
//  - 4 consecutive c * D3 floats = {4,12,20} floats = exact, 16B-aligned
//    float4 runs; consecutive threads tile the row contiguously ->
//    direct coalesced float4 stores, NO LDS, NO __syncthreads.
//  - weights still wave-uniform (s_load), but 4x fewer waves -> 4x less
//    scalar-load replay, and no ds_write traffic sharing lgkmcnt with it.

#define OUT1_BASE (512 * 12288)               // 6291456
#define OUT2_BASE (OUT1_BASE + 512 * 49152)   // 31457280

// One path (l1,l2,l3) with dims D1=2l1+1 etc.
// w: (D1,D2,D3) row-major.  a: D1 floats (i-side).  bv: 4 j's, layout
// bv[jj*D2+n].  op: output pointer for this thread's first c (M-fastest).
template<int D1, int D2, int D3>
__device__ __forceinline__ void do_path(const float* __restrict__ w,
                                        const float* a, const float* bv,
                                        float* __restrict__ op)
{
    // precontract a-side:  wa[n*D3+M] = sum_m w[(m*D2+n)*D3+M] * a[m]
    float wa[D2 * D3];
#pragma unroll
    for (int k = 0; k < D2 * D3; ++k) wa[k] = 0.f;
#pragma unroll
    for (int m = 0; m < D1; ++m) {
        const float am = a[m];
#pragma unroll
        for (int n = 0; n < D2; ++n)
#pragma unroll
            for (int M = 0; M < D3; ++M)
                wa[n * D3 + M] += w[(m * D2 + n) * D3 + M] * am;
    }

    // contract b-side for 4 j's:  o[jj*D3+M] = sum_n wa[n*D3+M] * b[jj][n]
    float o[4 * D3];
#pragma unroll
    for (int k = 0; k < 4 * D3; ++k) o[k] = 0.f;
#pragma unroll
    for (int jj = 0; jj < 4; ++jj)
#pragma unroll
        for (int n = 0; n < D2; ++n) {
            const float bb = bv[jj * D2 + n];
#pragma unroll
            for (int M = 0; M < D3; ++M)
                o[jj * D3 + M] += wa[n * D3 + M] * bb;
        }

    // 4*D3 floats = D3 float4s, 16B-aligned (c0 % 4 == 0)
#pragma unroll
    for (int q = 0; q < D3; ++q) {
        float4 v;
        v.x = o[4 * q + 0]; v.y = o[4 * q + 1];
        v.z = o[4 * q + 2]; v.w = o[4 * q + 3];
        *(float4*)(op + 4 * q) = v;
    }
}

__global__ __launch_bounds__(256) void tp_kernel(
    const float* __restrict__ x0, const float* __restrict__ x1, const float* __restrict__ x2,
    const float* __restrict__ w000, const float* __restrict__ w011, const float* __restrict__ w022,
    const float* __restrict__ w110, const float* __restrict__ w111, const float* __restrict__ w112,
    const float* __restrict__ w121, const float* __restrict__ w122,
    const float* __restrict__ w220, const float* __restrict__ w221, const float* __restrict__ w222,
    float* __restrict__ out)
{
    const int b   = blockIdx.x >> 2;        // 0..511
    const int seg = blockIdx.x & 3;         // 0..3
    const int t   = threadIdx.x;            // 0..255
    const int c0  = seg * 1024 + t * 4;     // first of 4 consecutive c
    const int i   = c0 >> 6;                // same for all 4 c (4t%64 <= 60)
    const int j0  = c0 & 63;                // multiple of 4

    // ---- a-side (i): shared by the thread's 4 outputs ----
    const float a0[1] = { x0[b * 64 + i] };
    float a1[3], a2[5];
#pragma unroll
    for (int m = 0; m < 3; ++m) a1[m] = x1[b * 192 + i * 3 + m];
#pragma unroll
    for (int m = 0; m < 5; ++m) a2[m] = x2[b * 320 + i * 5 + m];

    // ---- b-side (j0..j0+3): fully vectorized, all 16B-aligned ----
    float b0v[4], b1v[12], b2v[20];
    {
        const float4 v = *(const float4*)(x0 + b * 64 + j0);
        b0v[0] = v.x; b0v[1] = v.y; b0v[2] = v.z; b0v[3] = v.w;
    }
#pragma unroll
    for (int k = 0; k < 3; ++k) {
        const float4 v = *(const float4*)(x1 + b * 192 + j0 * 3 + 4 * k);
        b1v[4 * k + 0] = v.x; b1v[4 * k + 1] = v.y;
        b1v[4 * k + 2] = v.z; b1v[4 * k + 3] = v.w;
    }
#pragma unroll
    for (int k = 0; k < 5; ++k) {
        const float4 v = *(const float4*)(x2 + b * 320 + j0 * 5 + 4 * k);
        b2v[4 * k + 0] = v.x; b2v[4 * k + 1] = v.y;
        b2v[4 * k + 2] = v.z; b2v[4 * k + 3] = v.w;
    }

    float* __restrict__ o0 = out + b * 12288;          // out0 for this b
    float* __restrict__ o1 = out + OUT1_BASE + b * 49152;
    float* __restrict__ o2 = out + OUT2_BASE + b * 81920;

    // ---- pair (0,0) ----
    do_path<1, 1, 1>(w000, a0, b0v, o0 + 0 * 4096 + c0);          // (0,0,0) out0 chunk0

    // ---- pair (0,1) ----
    do_path<1, 3, 3>(w011, a0, b1v, o1 + 0 * 12288 + c0 * 3);     // (0,1,1) out1 chunk0

    // ---- pair (0,2) ----
    do_path<1, 5, 5>(w022, a0, b2v, o2 + 0 * 20480 + c0 * 5);     // (0,2,2) out2 chunk0

    // ---- pair (1,1) ----
    do_path<3, 3, 1>(w110, a1, b1v, o0 + 1 * 4096 + c0);          // (1,1,0) out0 chunk1
    do_path<3, 3, 3>(w111, a1, b1v, o1 + 1 * 12288 + c0 * 3);     // (1,1,1) out1 chunk1
    do_path<3, 3, 5>(w112, a1, b1v, o2 + 1 * 20480 + c0 * 5);     // (1,1,2) out2 chunk1

    // ---- pair (1,2) ----
    do_path<3, 5, 3>(w121, a1, b2v, o1 + 2 * 12288 + c0 * 3);     // (1,2,1) out1 chunk2
    do_path<3, 5, 5>(w122, a1, b2v, o2 + 2 * 20480 + c0 * 5);     // (1,2,2) out2 chunk2

    // ---- pair (2,2) ----
    do_path<5, 5, 1>(w220, a2, b2v, o0 + 2 * 4096 + c0);          // (2,2,0) out0 chunk2
    do_path<5, 5, 3>(w221, a2, b2v, o1 + 3 * 12288 + c0 * 3);     // (2,2,1) out1 chunk3
    do_path<5, 5, 5>(w222, a2, b2v, o2 + 3 * 20480 + c0 * 5);     // (2,2,2) out2 chunk3
}

extern "C" void kernel_launch(void* const* d_in, const int* in_sizes, int n_in,
                              void* d_out, int out_size, void* d_ws, size_t ws_size,
                              hipStream_t stream) {
    const float* x0   = (const float*)d_in[0];
    const float* x1   = (const float*)d_in[1];
    const float* x2   = (const float*)d_in[2];
    const float* w000 = (const float*)d_in[3];
    const float* w011 = (const float*)d_in[4];
    const float* w022 = (const float*)d_in[5];
    const float* w110 = (const float*)d_in[6];
    const float* w111 = (const float*)d_in[7];
    const float* w112 = (const float*)d_in[8];
    const float* w121 = (const float*)d_in[9];
    const float* w122 = (const float*)d_in[10];
    const float* w220 = (const float*)d_in[11];
    const float* w221 = (const float*)d_in[12];
    const float* w222 = (const float*)d_in[13];
    float* outp = (float*)d_out;

    // 512 b * 4 segments of 1024 c; 256 threads * 4 c each
    dim3 grid(512 * 4);
    dim3 block(256);
    tp_kernel<<<grid, block, 0, stream>>>(x0, x1, x2,
                                          w000, w011, w022, w110, w111, w112,
                                          w121, w122, w220, w221, w222, outp);
}

// Round 2
// 320.913 us; speedup vs baseline: 1.1178x; 1.1178x over previous
//
#include <hip/hip_runtime.h>

// Tensor-product nonlinearity, B=512, MUL=64, l in {0,1,2}.
// out0: (512, 3*4096, 1), out1: (512, 4*4096, 3), out2: (512, 4*4096, 5)
// flat-concatenated in d_out in that order.
//
// Round-4 design (J=4 compute + LDS-staged coalesced stores):
//  - each thread owns 4 consecutive c = i*64+j (same i). a-side
//    precontraction wa[n][M] = sum_m w[m][n][M]*a[m] amortized over 4 j's
//    -> total FMA ~halved, 4x fewer waves -> 4x less s_load replay.
//  - out1/out2 routed through a 32 KiB LDS buffer in 4 rounds (one out1
//    chunk + one out2 chunk per round), flushed as lane-contiguous float4
//    (16 B lane stride -> fully combined store transactions). Round-1's
//    direct 48/80-B-stride stores cost ~3.4x transactions - that was the
//    regression.
//  - staging ds_write_b128 at 48/80 B lane stride: 16B-block group = 3t&7 /
//    5t&7, bijective mod 8 -> even bank spread, no conflicts.
//  - out0 (D3=1) written direct: already lane-contiguous float4.

#define OUT1_BASE (512 * 12288)               // 6291456
#define OUT2_BASE (OUT1_BASE + 512 * 49152)   // 31457280

// One path (l1,l2,l3), dims D1=2l1+1 etc. w: (D1,D2,D3) row-major.
// a: D1 floats (i-side). bv: 4 j's, bv[jj*D2+n]. o: 4*D3 outputs,
// o[jj*D3+M] == chunk-local dwords [t*4*D3 .. ) in c-major M-fast order.
template<int D1, int D2, int D3>
__device__ __forceinline__ void path_compute(const float* __restrict__ w,
                                             const float* a, const float* bv,
                                             float* __restrict__ o)
{
    float wa[D2 * D3];
#pragma unroll
    for (int k = 0; k < D2 * D3; ++k) wa[k] = 0.f;
#pragma unroll
    for (int m = 0; m < D1; ++m) {
        const float am = a[m];
#pragma unroll
        for (int n = 0; n < D2; ++n)
#pragma unroll
            for (int M = 0; M < D3; ++M)
                wa[n * D3 + M] += w[(m * D2 + n) * D3 + M] * am;
    }
#pragma unroll
    for (int k = 0; k < 4 * D3; ++k) o[k] = 0.f;
#pragma unroll
    for (int jj = 0; jj < 4; ++jj)
#pragma unroll
        for (int n = 0; n < D2; ++n) {
            const float bb = bv[jj * D2 + n];
#pragma unroll
            for (int M = 0; M < D3; ++M)
                o[jj * D3 + M] += wa[n * D3 + M] * bb;
        }
}

template<int D3>
__device__ __forceinline__ void stage(float* __restrict__ s, int dwbase,
                                      const float* __restrict__ o)
{
#pragma unroll
    for (int q = 0; q < D3; ++q) {
        float4 v;
        v.x = o[4 * q + 0]; v.y = o[4 * q + 1];
        v.z = o[4 * q + 2]; v.w = o[4 * q + 3];
        *(float4*)(s + dwbase + 4 * q) = v;
    }
}

__device__ __forceinline__ void store_f4(float* __restrict__ p,
                                         const float* __restrict__ o)
{
    float4 v;
    v.x = o[0]; v.y = o[1]; v.z = o[2]; v.w = o[3];
    *(float4*)p = v;
}

__global__ __launch_bounds__(256) void tp_kernel(
    const float* __restrict__ x0, const float* __restrict__ x1, const float* __restrict__ x2,
    const float* __restrict__ w000, const float* __restrict__ w011, const float* __restrict__ w022,
    const float* __restrict__ w110, const float* __restrict__ w111, const float* __restrict__ w112,
    const float* __restrict__ w121, const float* __restrict__ w122,
    const float* __restrict__ w220, const float* __restrict__ w221, const float* __restrict__ w222,
    float* __restrict__ out)
{
    // dwords [0,3072): out1 chunk (c_local*3+M); [3072,8192): out2 chunk
    __shared__ __align__(16) float s_out[8192];   // 32 KiB

    const int b   = blockIdx.x >> 2;        // 0..511
    const int seg = blockIdx.x & 3;         // 0..3
    const int t   = threadIdx.x;            // 0..255
    const int c0  = seg * 1024 + t * 4;     // first of 4 consecutive c
    const int i   = c0 >> 6;                // same for all 4 c
    const int j0  = c0 & 63;                // multiple of 4

    // ---- a-side (i): shared by the thread's 4 outputs ----
    const float a0[1] = { x0[b * 64 + i] };
    float a1[3], a2[5];
#pragma unroll
    for (int m = 0; m < 3; ++m) a1[m] = x1[b * 192 + i * 3 + m];
#pragma unroll
    for (int m = 0; m < 5; ++m) a2[m] = x2[b * 320 + i * 5 + m];

    // ---- b-side (j0..j0+3): vectorized, all 16B-aligned ----
    float b0v[4], b1v[12], b2v[20];
    {
        const float4 v = *(const float4*)(x0 + b * 64 + j0);
        b0v[0] = v.x; b0v[1] = v.y; b0v[2] = v.z; b0v[3] = v.w;
    }
#pragma unroll
    for (int k = 0; k < 3; ++k) {
        const float4 v = *(const float4*)(x1 + b * 192 + j0 * 3 + 4 * k);
        b1v[4 * k + 0] = v.x; b1v[4 * k + 1] = v.y;
        b1v[4 * k + 2] = v.z; b1v[4 * k + 3] = v.w;
    }
#pragma unroll
    for (int k = 0; k < 5; ++k) {
        const float4 v = *(const float4*)(x2 + b * 320 + j0 * 5 + 4 * k);
        b2v[4 * k + 0] = v.x; b2v[4 * k + 1] = v.y;
        b2v[4 * k + 2] = v.z; b2v[4 * k + 3] = v.w;
    }

    float* __restrict__ o0 = out + b * 12288;
    // per-round flush bases (dwords), this block's 1024-c slice
    const int o1base = OUT1_BASE + b * 49152 + seg * 3072;
    const int o2base = OUT2_BASE + b * 81920 + seg * 5120;

    float o[20];

    // ================= round 0: (0,1,1) + (0,2,2), direct (0,0,0) ========
    {
        float oo[4];
#pragma unroll
        for (int jj = 0; jj < 4; ++jj) oo[jj] = w000[0] * (a0[0] * b0v[jj]);
        store_f4(o0 + c0, oo);
    }
    path_compute<1, 3, 3>(w011, a0, b1v, o);  stage<3>(s_out, t * 12, o);
    path_compute<1, 5, 5>(w022, a0, b2v, o);  stage<5>(s_out, 3072 + t * 20, o);

#pragma unroll
    for (int r = 0; r < 4; ++r) {
        __syncthreads();
        // ---- flush round r: 2048 lane-contiguous float4 = 8 per thread --
#pragma unroll
        for (int kk = 0; kk < 8; ++kk) {
            const int fi = kk * 256 + t;          // 0..2047, branch uniform
            float4 v = *(const float4*)(s_out + 4 * fi);
            int dst;
            if (fi < 768) dst = o1base + r * 12288 + 4 * fi;
            else          dst = o2base + r * 20480 + 4 * (fi - 768);
            *(float4*)(out + dst) = v;
        }
        if (r == 3) break;
        __syncthreads();

        // ---- compute + stage next round's pair -------------------------
        if (r == 0) {          // (1,1,1) + (1,1,2), direct (1,1,0)
            float oo[4];
            path_compute<3, 3, 1>(w110, a1, b1v, oo);
            store_f4(o0 + 4096 + c0, oo);
            path_compute<3, 3, 3>(w111, a1, b1v, o);  stage<3>(s_out, t * 12, o);
            path_compute<3, 3, 5>(w112, a1, b1v, o);  stage<5>(s_out, 3072 + t * 20, o);
        } else if (r == 1) {   // (1,2,1) + (1,2,2)
            path_compute<3, 5, 3>(w121, a1, b2v, o);  stage<3>(s_out, t * 12, o);
            path_compute<3, 5, 5>(w122, a1, b2v, o);  stage<5>(s_out, 3072 + t * 20, o);
        } else {               // (2,2,1) + (2,2,2), direct (2,2,0)
            float oo[4];
            path_compute<5, 5, 1>(w220, a2, b2v, oo);
            store_f4(o0 + 8192 + c0, oo);
            path_compute<5, 5, 3>(w221, a2, b2v, o);  stage<3>(s_out, t * 12, o);
            path_compute<5, 5, 5>(w222, a2, b2v, o);  stage<5>(s_out, 3072 + t * 20, o);
        }
    }
}

extern "C" void kernel_launch(void* const* d_in, const int* in_sizes, int n_in,
                              void* d_out, int out_size, void* d_ws, size_t ws_size,
                              hipStream_t stream) {
    const float* x0   = (const float*)d_in[0];
    const float* x1   = (const float*)d_in[1];
    const float* x2   = (const float*)d_in[2];
    const float* w000 = (const float*)d_in[3];
    const float* w011 = (const float*)d_in[4];
    const float* w022 = (const float*)d_in[5];
    const float* w110 = (const float*)d_in[6];
    const float* w111 = (const float*)d_in[7];
    const float* w112 = (const float*)d_in[8];
    const float* w121 = (const float*)d_in[9];
    const float* w122 = (const float*)d_in[10];
    const float* w220 = (const float*)d_in[11];
    const float* w221 = (const float*)d_in[12];
    const float* w222 = (const float*)d_in[13];
    float* outp = (float*)d_out;

    // 512 b * 4 segments of 1024 c; 256 threads * 4 c each
    dim3 grid(512 * 4);
    dim3 block(256);
    tp_kernel<<<grid, block, 0, stream>>>(x0, x1, x2,
                                          w000, w011, w022, w110, w111, w112,
                                          w121, w122, w220, w221, w222, outp);
}